// Round 12
// baseline (285.617 us; speedup 1.0000x reference)
//
#include <hip/hip_runtime.h>
#include <stdint.h>

#define N_NODES 50000
#define N_EDGES 800000
#define DIM     128
#define EBLK 782                 // edge blocks: ceil(800000/1024), 4 edges/thread
#define GEMM1BLK 391             // layer-1 GEMM tiles (128 rows each)
#define GNODES 16                // nodes per gather/fused block (50000 = 16*3125)
#define GGRID 3125
#define GCAP 2048                // LDS edge cap per block (mean 256)
#define G3NODES 128              // nodes per gather3 block (2 lanes/node)
#define G3CAP 4096               // LDS edge cap for gather3 blocks (mean 2048)
#define SCANBLK 196              // scan blocks: ceil(50001/256)

typedef __attribute__((ext_vector_type(8))) unsigned short ushort8_t;
typedef __attribute__((ext_vector_type(8))) short bfrag;    // 8 bf16 = 4 VGPR
typedef __attribute__((ext_vector_type(4))) float f32x4;

// ---------------- Threefry-2x32 (exact JAX 20-round) ----------------
__host__ __device__ inline void threefry2x32(uint32_t k0, uint32_t k1,
                                             uint32_t x0, uint32_t x1,
                                             uint32_t& o0, uint32_t& o1) {
    uint32_t ks0 = k0, ks1 = k1, ks2 = k0 ^ k1 ^ 0x1BD11BDAu;
    uint32_t v0 = x0 + ks0, v1 = x1 + ks1;
#define TF_R(r) { v0 += v1; v1 = (v1 << (r)) | (v1 >> (32 - (r))); v1 ^= v0; }
    TF_R(13) TF_R(15) TF_R(26) TF_R(6)
    v0 += ks1; v1 += ks2 + 1u;
    TF_R(17) TF_R(29) TF_R(16) TF_R(24)
    v0 += ks2; v1 += ks0 + 2u;
    TF_R(13) TF_R(15) TF_R(26) TF_R(6)
    v0 += ks0; v1 += ks1 + 3u;
    TF_R(17) TF_R(29) TF_R(16) TF_R(24)
    v0 += ks1; v1 += ks2 + 4u;
    TF_R(13) TF_R(15) TF_R(26) TF_R(6)
    v0 += ks2; v1 += ks0 + 5u;
#undef TF_R
    o0 = v0; o1 = v1;
}

__device__ inline float drop_scale(uint32_t kk0, uint32_t kk1, uint32_t i) {
    uint32_t b0, b1;
    threefry2x32(kk0, kk1, 0u, i, b0, b1);
    uint32_t bits = b0 ^ b1;               // partitionable 32-bit path (verified R0)
    return (bits >> 31) ? 0.0f : 2.0f;     // keep iff u < 0.5 iff top bit 0
}

__device__ inline float bf2f(ushort u) {
    return __uint_as_float(((uint32_t)u) << 16);
}
__device__ inline float bfpair_lo(uint32_t u) { return __uint_as_float(u << 16); }
__device__ inline float bfpair_hi(uint32_t u) { return __uint_as_float(u & 0xffff0000u); }

__device__ inline ushort f2bf_rne(float f) {
    uint32_t bits = __float_as_uint(f);
    uint32_t lsb = (bits >> 16) & 1u;
    bits += 0x7fffu + lsb;                 // round-to-nearest-even
    return (ushort)(bits >> 16);
}

// 8-feat accumulate from a uint4 of bf16 pairs (dword-wise unpack: 1 VALU/elem)
__device__ inline void acc8(float* acc, uint4 u, float d) {
    acc[0] += d * bfpair_lo(u.x); acc[1] += d * bfpair_hi(u.x);
    acc[2] += d * bfpair_lo(u.y); acc[3] += d * bfpair_hi(u.y);
    acc[4] += d * bfpair_lo(u.z); acc[5] += d * bfpair_hi(u.z);
    acc[6] += d * bfpair_lo(u.w); acc[7] += d * bfpair_hi(u.w);
}
__device__ inline void acc8p(float* acc, uint4 u) {
    acc[0] += bfpair_lo(u.x); acc[1] += bfpair_hi(u.x);
    acc[2] += bfpair_lo(u.y); acc[3] += bfpair_hi(u.y);
    acc[4] += bfpair_lo(u.z); acc[5] += bfpair_hi(u.z);
    acc[6] += bfpair_lo(u.w); acc[7] += bfpair_hi(u.w);
}

// ---------------- MFMA GEMM body (layer-1, fused into k_fillcol) ------------
// F32A=1: A read from fp32, converted in registers. SCALE=0: raw output
// (dis may not be globally visible to these blocks; gather applies dis[s]).
template<int F32A, int SCALE>
__device__ inline void gemm_body(const ushort* __restrict__ Xb,
                                 const float* __restrict__ Xf,
                                 const ushort* __restrict__ Wt,
                                 const float* __restrict__ dis,
                                 ushort* __restrict__ Hb, int gb, int tid) {
    int w = tid >> 6, lane = tid & 63;
    int m0 = gb * 128 + w * 32;
    int lrow = lane & 15, quad = lane >> 4;
    f32x4 acc[2][8] = {};
    for (int kt = 0; kt < DIM; kt += 32) {
        bfrag a[2], b[8];
        #pragma unroll
        for (int t = 0; t < 2; ++t) {
            int m = m0 + t * 16 + lrow;
            if (m >= N_NODES) m = 0;
            if (F32A) {
                const float* p = Xf + (size_t)m * DIM + kt + quad * 8;
                f32x4 v0 = *(const f32x4*)p;
                f32x4 v1 = *(const f32x4*)(p + 4);
                #pragma unroll
                for (int j = 0; j < 4; ++j) {
                    a[t][j]     = (short)f2bf_rne(v0[j]);
                    a[t][j + 4] = (short)f2bf_rne(v1[j]);
                }
            } else {
                a[t] = *(const bfrag*)(Xb + (size_t)m * DIM + kt + quad * 8);
            }
        }
        #pragma unroll
        for (int c = 0; c < 8; ++c) {
            int n = c * 16 + lrow;
            b[c] = *(const bfrag*)(Wt + (size_t)n * DIM + kt + quad * 8);
        }
        #pragma unroll
        for (int t = 0; t < 2; ++t)
            #pragma unroll
            for (int c = 0; c < 8; ++c)
                acc[t][c] = __builtin_amdgcn_mfma_f32_16x16x32_bf16(a[t], b[c], acc[t][c], 0, 0, 0);
    }
    #pragma unroll
    for (int t = 0; t < 2; ++t) {
        #pragma unroll
        for (int r = 0; r < 4; ++r) {
            int rowi = m0 + t * 16 + quad * 4 + r;
            if (rowi < N_NODES) {
                float dv = SCALE ? dis[rowi] : 1.0f;
                #pragma unroll
                for (int c = 0; c < 8; ++c) {
                    int feat = c * 16 + lrow;
                    float z = SCALE ? acc[t][c][r] * dv : acc[t][c][r];
                    Hb[(size_t)rowi * DIM + feat] = f2bf_rne(z);
                }
            }
        }
    }
}

// ---- k_deg: direct degree count, 800K-way parallel (old bucket scatter was
// 391 blocks / 1.5 per CU and ~44us). Edge blocks first (latency-bound),
// W transposes after. deg[] pre-zeroed by the memset.
__global__ __launch_bounds__(256) void k_deg(const int* __restrict__ dst,
                                             uint32_t* __restrict__ deg,
                                             const float* __restrict__ W1,
                                             const float* __restrict__ W2,
                                             ushort* __restrict__ W1t,
                                             ushort* __restrict__ W2t) {
    int b = blockIdx.x;
    int t = threadIdx.x;
    if (b < EBLK) {
        int base = b * 1024;
        #pragma unroll
        for (int i = 0; i < 4; ++i) {
            int e = base + i * 256 + t;
            if (e < N_EDGES) atomicAdd(&deg[(uint32_t)dst[e]], 1u);
        }
    } else {
        int j = (b - EBLK) * 256 + t;              // 0..32767
        const float* W = (j < DIM * DIM) ? W1 : W2;
        ushort* Wt = (j < DIM * DIM) ? W1t : W2t;
        int i = j & (DIM * DIM - 1);
        int k = i >> 7, n = i & 127;
        Wt[n * DIM + k] = f2bf_rne(W[k * DIM + n]);
    }
}

// ---- k_scan: block b = nodes [256b, 256b+256). cbase = sum deg[0..256b)
// (redundant coalesced L2-hot reads — cheaper than a cross-kernel scan), then
// LDS-scan own 256; writes row, cur (fill cursor), dis.
__global__ __launch_bounds__(256) void k_scan(const uint32_t* __restrict__ deg,
                                              uint32_t* __restrict__ row,
                                              uint32_t* __restrict__ cur,
                                              float* __restrict__ dis) {
    __shared__ uint32_t red[256];
    __shared__ uint32_t scan[256];
    int b = blockIdx.x;
    int t = threadIdx.x;
    int nbase = b * 256;
    uint32_t p = 0;
    for (int i = t; i < nbase; i += 256) p += deg[i];
    red[t] = p;
    __syncthreads();
    for (int off = 128; off > 0; off >>= 1) {
        if (t < off) red[t] += red[t + off];
        __syncthreads();
    }
    uint32_t cbase = red[0];
    int v = nbase + t;
    uint32_t myd = (v < N_NODES) ? deg[v] : 0u;
    scan[t] = myd;
    __syncthreads();
    for (int off = 1; off < 256; off <<= 1) {
        uint32_t xx = (t >= off) ? scan[t - off] : 0u;
        __syncthreads();
        scan[t] += xx;
        __syncthreads();
    }
    uint32_t excl = scan[t] - myd;
    if (v <= N_NODES) row[v] = cbase + excl;       // row[50000] = 800000
    if (v < N_NODES) {
        cur[v] = cbase + excl;
        dis[v] = 1.0f / sqrtf((float)(myd + 1u));
    }
}

// ---- k_fillcol: direct CSR fill (randomly-ordered neighbor lists — sum-order
// nondeterminism was already present in the old bucket scheme), fused with the
// layer-1 GEMM blocks (no dependency between them; fill first, R18).
__global__ __launch_bounds__(256) void k_fillcol(const int* __restrict__ src,
                                                 const int* __restrict__ dst,
                                                 uint32_t* __restrict__ cur,
                                                 ushort* __restrict__ col16,
                                                 const float* __restrict__ x,
                                                 const ushort* __restrict__ W1t,
                                                 ushort* __restrict__ Hb) {
    int b = blockIdx.x;
    int t = threadIdx.x;
    if (b < EBLK) {
        int base = b * 1024;
        #pragma unroll
        for (int i = 0; i < 4; ++i) {
            int e = base + i * 256 + t;
            if (e < N_EDGES) {
                uint32_t d = (uint32_t)dst[e];
                uint32_t s = (uint32_t)src[e];
                uint32_t pos = atomicAdd(&cur[d], 1u);
                col16[pos] = (ushort)s;
            }
        }
    } else {
        gemm_body<1, 0>(nullptr, x, W1t, nullptr, Hb, b - EBLK, t);
    }
}

// ---------------- FUSED gather1 + gemm2, 16-node tile, LDS-staged A ----------
// Phase 1: gather (16 lanes/node, 8/4/1 MLP cascade) + bias/leaky/dropout ->
// post-act tile in LDS (XOR-swizzled, G4). Phase 2: 16-row MFMA GEMM from
// LDS; Hb2 dis-prescaled. (R8-best version.)
__global__ __launch_bounds__(256) void k_fused(const uint32_t* __restrict__ row,
                                               const ushort* __restrict__ col16,
                                               const float* __restrict__ dis,
                                               const ushort* __restrict__ Hb,
                                               const float* __restrict__ bias,
                                               const ushort* __restrict__ W2t,
                                               ushort* __restrict__ Hb2,
                                               uint32_t kk0, uint32_t kk1) {
    __shared__ ushort scol[GCAP];
    __shared__ uint32_t srow[GNODES + 1];
    __shared__ ushort At[GNODES * DIM];          // post-act tile, swizzled
    int tid = threadIdx.x;
    int nbase = blockIdx.x * GNODES;
    if (tid <= GNODES) srow[tid] = row[nbase + tid];
    __syncthreads();
    uint32_t eLo = srow[0];
    uint32_t count = srow[GNODES] - eLo;
    bool staged = count <= GCAP;
    if (staged) {
        for (uint32_t i = tid; i < count; i += 256) scol[i] = col16[eLo + i];
    }
    __syncthreads();

    // ---- phase 1: gather + epilogue -> LDS tile ----
    int nl = tid >> 4;                 // node in block (0..15)
    int q  = tid & 15;                 // 8-feat slice (0..15)
    int v = nbase + nl;                // always < N_NODES (50000 = 16*3125)
    float dv = dis[v];
    float acc[8];
    {
        uint4 u = *(const uint4*)(Hb + (size_t)v * DIM + q * 8);
        acc[0] = bfpair_lo(u.x); acc[1] = bfpair_hi(u.x);
        acc[2] = bfpair_lo(u.y); acc[3] = bfpair_hi(u.y);
        acc[4] = bfpair_lo(u.z); acc[5] = bfpair_hi(u.z);
        acc[6] = bfpair_lo(u.w); acc[7] = bfpair_hi(u.w);
        #pragma unroll
        for (int j = 0; j < 8; ++j) acc[j] *= dv;   // self-loop (Hb unscaled)
    }
    uint32_t e0 = srow[nl] - eLo, e1 = srow[nl + 1] - eLo;
    uint32_t e = e0;
    if (staged) {
        for (; e + 8 <= e1; e += 8) {      // 8 rows in flight (MLP)
            uint32_t s0 = scol[e],     s1 = scol[e + 1];
            uint32_t s2 = scol[e + 2], s3 = scol[e + 3];
            uint32_t s4 = scol[e + 4], s5 = scol[e + 5];
            uint32_t s6 = scol[e + 6], s7 = scol[e + 7];
            uint4 u0 = *(const uint4*)(Hb + (size_t)s0 * DIM + q * 8);
            uint4 u1 = *(const uint4*)(Hb + (size_t)s1 * DIM + q * 8);
            uint4 u2 = *(const uint4*)(Hb + (size_t)s2 * DIM + q * 8);
            uint4 u3 = *(const uint4*)(Hb + (size_t)s3 * DIM + q * 8);
            uint4 u4 = *(const uint4*)(Hb + (size_t)s4 * DIM + q * 8);
            uint4 u5 = *(const uint4*)(Hb + (size_t)s5 * DIM + q * 8);
            uint4 u6 = *(const uint4*)(Hb + (size_t)s6 * DIM + q * 8);
            uint4 u7 = *(const uint4*)(Hb + (size_t)s7 * DIM + q * 8);
            float d0 = dis[s0], d1 = dis[s1], d2 = dis[s2], d3 = dis[s3];
            float d4 = dis[s4], d5 = dis[s5], d6 = dis[s6], d7 = dis[s7];
            acc8(acc, u0, d0); acc8(acc, u1, d1);
            acc8(acc, u2, d2); acc8(acc, u3, d3);
            acc8(acc, u4, d4); acc8(acc, u5, d5);
            acc8(acc, u6, d6); acc8(acc, u7, d7);
        }
        for (; e + 4 <= e1; e += 4) {
            uint32_t s0 = scol[e],     s1 = scol[e + 1];
            uint32_t s2 = scol[e + 2], s3 = scol[e + 3];
            uint4 u0 = *(const uint4*)(Hb + (size_t)s0 * DIM + q * 8);
            uint4 u1 = *(const uint4*)(Hb + (size_t)s1 * DIM + q * 8);
            uint4 u2 = *(const uint4*)(Hb + (size_t)s2 * DIM + q * 8);
            uint4 u3 = *(const uint4*)(Hb + (size_t)s3 * DIM + q * 8);
            float d0 = dis[s0], d1 = dis[s1], d2 = dis[s2], d3 = dis[s3];
            acc8(acc, u0, d0); acc8(acc, u1, d1);
            acc8(acc, u2, d2); acc8(acc, u3, d3);
        }
        for (; e < e1; ++e) {
            uint32_t s0 = scol[e];
            uint4 u0 = *(const uint4*)(Hb + (size_t)s0 * DIM + q * 8);
            acc8(acc, u0, dis[s0]);
        }
    } else {
        for (; e < e1; ++e) {
            uint32_t s0 = col16[eLo + e];
            uint4 u0 = *(const uint4*)(Hb + (size_t)s0 * DIM + q * 8);
            acc8(acc, u0, dis[s0]);
        }
    }
    {
        int cbase = q * 8;
        uint32_t ibase = (uint32_t)(v * DIM + cbase);
        ushort8_t o;
        #pragma unroll
        for (int j = 0; j < 8; ++j) {
            float z = acc[j] * dv + bias[cbase + j];
            z = (z >= 0.f) ? z : 0.01f * z;
            z *= drop_scale(kk0, kk1, ibase + j);
            o[j] = f2bf_rne(z);
        }
        // swizzled store: idx = row*128 + (q*8 ^ ((row&7)<<3))
        *((ushort8_t*)(At + nl * DIM + ((q * 8) ^ ((nl & 7) << 3)))) = o;
    }
    __syncthreads();

    // ---- phase 2: 16-row GEMM: Hb2[tile] = (At @ W2) * dis ----
    int w = tid >> 6, lane = tid & 63;
    int lrow = lane & 15, quad = lane >> 4;
    int swz = (lrow & 7) << 3;
    f32x4 acc2[2] = {};
    for (int kt = 0; kt < DIM; kt += 32) {
        int k = kt + quad * 8;
        bfrag a = *(const bfrag*)(At + lrow * DIM + (k ^ swz));
        #pragma unroll
        for (int ct = 0; ct < 2; ++ct) {
            int n = (w * 2 + ct) * 16 + lrow;
            bfrag b = *(const bfrag*)(W2t + (size_t)n * DIM + k);
            acc2[ct] = __builtin_amdgcn_mfma_f32_16x16x32_bf16(a, b, acc2[ct], 0, 0, 0);
        }
    }
    #pragma unroll
    for (int ct = 0; ct < 2; ++ct) {
        #pragma unroll
        for (int rr = 0; rr < 4; ++rr) {
            int rowi = nbase + quad * 4 + rr;
            float dvv = dis[rowi];
            int feat = (w * 2 + ct) * 16 + lrow;
            Hb2[(size_t)rowi * DIM + feat] = f2bf_rne(acc2[ct][rr] * dvv);
        }
    }
}

// ---------------- gather2: aggregation + bias + leaky + dropout + classifier -
// Block = 16 nodes, 16 lanes/node, 8/4/1 cascade. Hb2 rows are dis-prescaled.
// Classifier: 128->2 dot folded in, 16-lane shfl reduce, one atomic pair per
// node into h3s. (R8-best version.)
__global__ __launch_bounds__(256) void k_gather2(const uint32_t* __restrict__ row,
                                                 const ushort* __restrict__ col16,
                                                 const float* __restrict__ dis,
                                                 const ushort* __restrict__ Hb,
                                                 const float* __restrict__ bias,
                                                 const float* __restrict__ W3,
                                                 float* __restrict__ h3s,
                                                 uint32_t kk0, uint32_t kk1) {
    __shared__ ushort scol[GCAP];
    __shared__ uint32_t srow[GNODES + 1];
    int tid = threadIdx.x;
    int nbase = blockIdx.x * GNODES;
    if (tid <= GNODES) srow[tid] = row[nbase + tid];
    __syncthreads();
    uint32_t eLo = srow[0];
    uint32_t count = srow[GNODES] - eLo;
    bool staged = count <= GCAP;
    if (staged) {
        for (uint32_t i = tid; i < count; i += 256) scol[i] = col16[eLo + i];
    }
    __syncthreads();

    int nl = tid >> 4;                 // node in block (0..15)
    int q  = tid & 15;                 // 8-feat slice (0..15)
    int v = nbase + nl;                // always < N_NODES (50000 = 16*3125)
    float dv = dis[v];
    float acc[8];
    {
        uint4 u = *(const uint4*)(Hb + (size_t)v * DIM + q * 8);
        acc[0] = bfpair_lo(u.x); acc[1] = bfpair_hi(u.x);
        acc[2] = bfpair_lo(u.y); acc[3] = bfpair_hi(u.y);
        acc[4] = bfpair_lo(u.z); acc[5] = bfpair_hi(u.z);
        acc[6] = bfpair_lo(u.w); acc[7] = bfpair_hi(u.w);
    }

    uint32_t e0 = srow[nl] - eLo, e1 = srow[nl + 1] - eLo;
    uint32_t e = e0;
    if (staged) {
        for (; e + 8 <= e1; e += 8) {
            uint32_t s0 = scol[e],     s1 = scol[e + 1];
            uint32_t s2 = scol[e + 2], s3 = scol[e + 3];
            uint32_t s4 = scol[e + 4], s5 = scol[e + 5];
            uint32_t s6 = scol[e + 6], s7 = scol[e + 7];
            uint4 u0 = *(const uint4*)(Hb + (size_t)s0 * DIM + q * 8);
            uint4 u1 = *(const uint4*)(Hb + (size_t)s1 * DIM + q * 8);
            uint4 u2 = *(const uint4*)(Hb + (size_t)s2 * DIM + q * 8);
            uint4 u3 = *(const uint4*)(Hb + (size_t)s3 * DIM + q * 8);
            uint4 u4 = *(const uint4*)(Hb + (size_t)s4 * DIM + q * 8);
            uint4 u5 = *(const uint4*)(Hb + (size_t)s5 * DIM + q * 8);
            uint4 u6 = *(const uint4*)(Hb + (size_t)s6 * DIM + q * 8);
            uint4 u7 = *(const uint4*)(Hb + (size_t)s7 * DIM + q * 8);
            acc8p(acc, u0); acc8p(acc, u1); acc8p(acc, u2); acc8p(acc, u3);
            acc8p(acc, u4); acc8p(acc, u5); acc8p(acc, u6); acc8p(acc, u7);
        }
        for (; e + 4 <= e1; e += 4) {
            uint32_t s0 = scol[e],     s1 = scol[e + 1];
            uint32_t s2 = scol[e + 2], s3 = scol[e + 3];
            uint4 u0 = *(const uint4*)(Hb + (size_t)s0 * DIM + q * 8);
            uint4 u1 = *(const uint4*)(Hb + (size_t)s1 * DIM + q * 8);
            uint4 u2 = *(const uint4*)(Hb + (size_t)s2 * DIM + q * 8);
            uint4 u3 = *(const uint4*)(Hb + (size_t)s3 * DIM + q * 8);
            acc8p(acc, u0); acc8p(acc, u1); acc8p(acc, u2); acc8p(acc, u3);
        }
        for (; e < e1; ++e) {
            uint4 u0 = *(const uint4*)(Hb + (size_t)scol[e] * DIM + q * 8);
            acc8p(acc, u0);
        }
    } else {
        for (; e < e1; ++e) {
            uint4 u0 = *(const uint4*)(Hb + (size_t)col16[eLo + e] * DIM + q * 8);
            acc8p(acc, u0);
        }
    }

    int cbase = q * 8;
    uint32_t ibase = (uint32_t)(v * DIM + cbase);
    float o0 = 0.f, o1 = 0.f;
    #pragma unroll
    for (int j = 0; j < 8; ++j) {
        float z = acc[j] * dv + bias[cbase + j];
        z = (z >= 0.f) ? z : 0.01f * z;
        z *= drop_scale(kk0, kk1, ibase + j);
        o0 += z * W3[(cbase + j) * 2 + 0];
        o1 += z * W3[(cbase + j) * 2 + 1];
    }
    // reduce the 16 q-lanes (consecutive lanes, same node)
    o0 += __shfl_xor(o0, 1); o0 += __shfl_xor(o0, 2);
    o0 += __shfl_xor(o0, 4); o0 += __shfl_xor(o0, 8);
    o1 += __shfl_xor(o1, 1); o1 += __shfl_xor(o1, 2);
    o1 += __shfl_xor(o1, 4); o1 += __shfl_xor(o1, 8);
    if (q == 0) {
        atomicAdd(&h3s[v * 2 + 0], o0 * dv);   // src-side dis for layer 3
        atomicAdd(&h3s[v * 2 + 1], o1 * dv);
    }
}

// ---------------- fused layer-3 gather + bias + log_softmax, LDS-staged ------
// 2 lanes/node (alternate edges) halves the divergent serial loop; shfl_xor(1)
// combines the two partials.
__global__ __launch_bounds__(256) void k_gather3(const uint32_t* __restrict__ row,
                                                 const ushort* __restrict__ col16,
                                                 const float* __restrict__ dis,
                                                 const float* __restrict__ H3s,
                                                 const float* __restrict__ b3,
                                                 float* __restrict__ out) {
    __shared__ ushort scol[G3CAP];
    __shared__ uint32_t srow[G3NODES + 1];
    int tid = threadIdx.x;
    int nbase = blockIdx.x * G3NODES;
    int nend = nbase + G3NODES; if (nend > N_NODES) nend = N_NODES;
    int nloc = nend - nbase;
    for (int i = tid; i <= nloc; i += 256) srow[i] = row[nbase + i];
    __syncthreads();
    uint32_t eLo = srow[0];
    uint32_t count = srow[nloc] - eLo;
    bool staged = count <= G3CAP;
    if (staged) {
        for (uint32_t i = tid; i < count; i += 256) scol[i] = col16[eLo + i];
    }
    __syncthreads();

    int nl = tid >> 1;                 // node in block
    int par = tid & 1;                 // edge-parity lane
    int v = nbase + nl;
    if (v >= N_NODES) return;
    const float2* H2 = (const float2*)H3s;
    float z0 = 0.f, z1 = 0.f;
    if (par == 0) {                    // self term once
        float2 h = H2[v];
        z0 = h.x; z1 = h.y;
    }
    uint32_t e0 = srow[nl] - eLo, e1 = srow[nl + 1] - eLo;
    if (staged) {
        for (uint32_t e = e0 + par; e < e1; e += 2) {
            float2 ha = H2[scol[e]];
            z0 += ha.x; z1 += ha.y;
        }
    } else {
        for (uint32_t e = e0 + par; e < e1; e += 2) {
            float2 ha = H2[col16[eLo + e]];
            z0 += ha.x; z1 += ha.y;
        }
    }
    z0 += __shfl_xor(z0, 1);
    z1 += __shfl_xor(z1, 1);
    if (par) return;
    float dv = dis[v];
    z0 = z0 * dv + b3[0];
    z1 = z1 * dv + b3[1];
    float m = fmaxf(z0, z1);
    float lse = m + logf(expf(z0 - m) + expf(z1 - m));
    out[v * 2 + 0] = z0 - lse;
    out[v * 2 + 1] = z1 - lse;
}

extern "C" void kernel_launch(void* const* d_in, const int* in_sizes, int n_in,
                              void* d_out, int out_size, void* d_ws, size_t ws_size,
                              hipStream_t stream) {
    const float* x  = (const float*)d_in[0];
    const int*   ei = (const int*)d_in[1];
    const float* W1 = (const float*)d_in[2];
    const float* b1 = (const float*)d_in[3];
    const float* W2 = (const float*)d_in[4];
    const float* b2 = (const float*)d_in[5];
    const float* W3 = (const float*)d_in[6];
    const float* b3 = (const float*)d_in[7];
    float* out = (float*)d_out;

    const int* src = ei;
    const int* dst = ei + N_EDGES;

    // workspace layout (u32 units) -- all regions disjoint. R11 bug fixed:
    // Hb = 50000*128 u16 = 3,200,000 u32 (NOT 1.6M). Explicit extents:
    //   deg   [0,        50176)
    //   cur   [50176,    100352)
    //   h3s   [100352,   200448)   (100000 used)
    //   row   [200448,   250752)   (50001 used)
    //   dis   [250752,   300800)
    //   col16 [300800,   700800)   (800000 u16 = 400000 u32)
    //   Hb    [700800,   3900800)  (6.4M u16 = 3.2M u32)
    //   Hb2   [3900800,  7100800)  (6.4M u16 = 3.2M u32)
    //   W1t   [7100800,  7108992)
    //   W2t   [7108992,  7117184)
    uint32_t* wsu = (uint32_t*)d_ws;
    float*    wsf = (float*)d_ws;
    uint32_t* deg    = wsu;
    uint32_t* cur    = wsu + 50176;
    float*    h3s    = wsf + 100352;
    uint32_t* row    = wsu + 200448;
    float*    dis    = wsf + 250752;
    ushort*   col16  = (ushort*)(wsu + 300800);
    ushort*   Hb     = (ushort*)(wsu + 700800);
    ushort*   Hb2    = (ushort*)(wsu + 3900800);
    ushort*   W1t    = (ushort*)(wsu + 7100800);
    ushort*   W2t    = (ushort*)(wsu + 7108992);

    // dropout keys: threefry-partitionable fold-like split of key(42) (verified R0)
    uint32_t k1a, k1b, k2a, k2b;
    threefry2x32(0u, 42u, 0u, 0u, k1a, k1b);
    threefry2x32(0u, 42u, 0u, 1u, k2a, k2b);

    // one memset covers deg + cur + h3s
    hipMemsetAsync(wsu, 0, 200448 * sizeof(uint32_t), stream);

    // ---- degree count (800K-way parallel) | W transposes ----
    k_deg<<<EBLK + 128, 256, 0, stream>>>(dst, deg, W1, W2, W1t, W2t);

    // ---- scan: row / cur / dis ----
    k_scan<<<SCANBLK, 256, 0, stream>>>(deg, row, cur, dis);

    // ---- CSR fill (direct, atomic cursors) OVERLAPPED with layer-1 GEMM ----
    k_fillcol<<<EBLK + GEMM1BLK, 256, 0, stream>>>(src, dst, cur, col16,
                                                   x, W1t, Hb);

    // ---- FUSED: layer-1 gather (+bias/leaky/dropout) + layer-2 GEMM ----
    k_fused<<<GGRID, 256, 0, stream>>>(row, col16, dis, Hb, b1, W2t, Hb2,
                                       k1a, k1b);

    // ---- layer-2 gather + fused classifier ----
    k_gather2<<<GGRID, 256, 0, stream>>>(row, col16, dis, Hb2, b2, W3, h3s,
                                         k2a, k2b);

    // ---- layer 3 aggregate + log_softmax ----
    k_gather3<<<(N_NODES + G3NODES - 1) / G3NODES, 256, 0, stream>>>(row, col16, dis,
                                                                     h3s, b3, out);
}

// Round 13
// 211.434 us; speedup vs baseline: 1.3509x; 1.3509x over previous
//
#include <hip/hip_runtime.h>
#include <stdint.h>

#define N_NODES 50000
#define N_EDGES 800000
#define DIM     128
#define NB   196                 // dst buckets: dst>>8
#define CAP  8192                // fixed slots per bucket in 'packed'
#define CHUNK 1024               // edges per scatter block (R13: was 2048 -> 2x TLP)
#define NBLK 782                 // ceil(800000/1024)
#define GNODES 16                // nodes per gather/fused block (50000 = 16*3125)
#define GGRID 3125
#define GCAP 2048                // LDS edge cap per block (mean 256)
#define G3NODES 128              // nodes per gather3 block (2 lanes/node)
#define G3CAP 4096               // LDS edge cap for gather3 blocks (mean 2048)
#define ZBLK 98                  // h3s zero blocks: 25000 f32x4 / 256

typedef __attribute__((ext_vector_type(8))) unsigned short ushort8_t;
typedef __attribute__((ext_vector_type(8))) short bfrag;    // 8 bf16 = 4 VGPR
typedef __attribute__((ext_vector_type(4))) float f32x4;

// ---------------- Threefry-2x32 (exact JAX 20-round) ----------------
__host__ __device__ inline void threefry2x32(uint32_t k0, uint32_t k1,
                                             uint32_t x0, uint32_t x1,
                                             uint32_t& o0, uint32_t& o1) {
    uint32_t ks0 = k0, ks1 = k1, ks2 = k0 ^ k1 ^ 0x1BD11BDAu;
    uint32_t v0 = x0 + ks0, v1 = x1 + ks1;
#define TF_R(r) { v0 += v1; v1 = (v1 << (r)) | (v1 >> (32 - (r))); v1 ^= v0; }
    TF_R(13) TF_R(15) TF_R(26) TF_R(6)
    v0 += ks1; v1 += ks2 + 1u;
    TF_R(17) TF_R(29) TF_R(16) TF_R(24)
    v0 += ks2; v1 += ks0 + 2u;
    TF_R(13) TF_R(15) TF_R(26) TF_R(6)
    v0 += ks0; v1 += ks1 + 3u;
    TF_R(17) TF_R(29) TF_R(16) TF_R(24)
    v0 += ks1; v1 += ks2 + 4u;
    TF_R(13) TF_R(15) TF_R(26) TF_R(6)
    v0 += ks2; v1 += ks0 + 5u;
#undef TF_R
    o0 = v0; o1 = v1;
}

__device__ inline float drop_scale(uint32_t kk0, uint32_t kk1, uint32_t i) {
    uint32_t b0, b1;
    threefry2x32(kk0, kk1, 0u, i, b0, b1);
    uint32_t bits = b0 ^ b1;               // partitionable 32-bit path (verified R0)
    return (bits >> 31) ? 0.0f : 2.0f;     // keep iff u < 0.5 iff top bit 0
}

__device__ inline float bf2f(ushort u) {
    return __uint_as_float(((uint32_t)u) << 16);
}
__device__ inline float bfpair_lo(uint32_t u) { return __uint_as_float(u << 16); }
__device__ inline float bfpair_hi(uint32_t u) { return __uint_as_float(u & 0xffff0000u); }

__device__ inline ushort f2bf_rne(float f) {
    uint32_t bits = __float_as_uint(f);
    uint32_t lsb = (bits >> 16) & 1u;
    bits += 0x7fffu + lsb;                 // round-to-nearest-even
    return (ushort)(bits >> 16);
}

// 8-feat accumulate from a uint4 of bf16 pairs (dword-wise unpack: 1 VALU/elem)
__device__ inline void acc8(float* acc, uint4 u, float d) {
    acc[0] += d * bfpair_lo(u.x); acc[1] += d * bfpair_hi(u.x);
    acc[2] += d * bfpair_lo(u.y); acc[3] += d * bfpair_hi(u.y);
    acc[4] += d * bfpair_lo(u.z); acc[5] += d * bfpair_hi(u.z);
    acc[6] += d * bfpair_lo(u.w); acc[7] += d * bfpair_hi(u.w);
}
__device__ inline void acc8p(float* acc, uint4 u) {
    acc[0] += bfpair_lo(u.x); acc[1] += bfpair_hi(u.x);
    acc[2] += bfpair_lo(u.y); acc[3] += bfpair_hi(u.y);
    acc[4] += bfpair_lo(u.z); acc[5] += bfpair_hi(u.z);
    acc[6] += bfpair_lo(u.w); acc[7] += bfpair_hi(u.w);
}

// ---------------- MFMA GEMM body (layer-1 inside k_fill): Hb[v][128] --------
// F32A=1: A read from fp32, converted in registers. SCALE=0: raw output
// (dis not ready while csr blocks run; gather applies dis[s] per edge).
template<int F32A, int SCALE>
__device__ inline void gemm_body(const ushort* __restrict__ Xb,
                                 const float* __restrict__ Xf,
                                 const ushort* __restrict__ Wt,
                                 const float* __restrict__ dis,
                                 ushort* __restrict__ Hb, int gb, int tid) {
    int w = tid >> 6, lane = tid & 63;
    int m0 = gb * 128 + w * 32;
    int lrow = lane & 15, quad = lane >> 4;
    f32x4 acc[2][8] = {};
    for (int kt = 0; kt < DIM; kt += 32) {
        bfrag a[2], b[8];
        #pragma unroll
        for (int t = 0; t < 2; ++t) {
            int m = m0 + t * 16 + lrow;
            if (m >= N_NODES) m = 0;
            if (F32A) {
                const float* p = Xf + (size_t)m * DIM + kt + quad * 8;
                f32x4 v0 = *(const f32x4*)p;
                f32x4 v1 = *(const f32x4*)(p + 4);
                #pragma unroll
                for (int j = 0; j < 4; ++j) {
                    a[t][j]     = (short)f2bf_rne(v0[j]);
                    a[t][j + 4] = (short)f2bf_rne(v1[j]);
                }
            } else {
                a[t] = *(const bfrag*)(Xb + (size_t)m * DIM + kt + quad * 8);
            }
        }
        #pragma unroll
        for (int c = 0; c < 8; ++c) {
            int n = c * 16 + lrow;
            b[c] = *(const bfrag*)(Wt + (size_t)n * DIM + kt + quad * 8);
        }
        #pragma unroll
        for (int t = 0; t < 2; ++t)
            #pragma unroll
            for (int c = 0; c < 8; ++c)
                acc[t][c] = __builtin_amdgcn_mfma_f32_16x16x32_bf16(a[t], b[c], acc[t][c], 0, 0, 0);
    }
    #pragma unroll
    for (int t = 0; t < 2; ++t) {
        #pragma unroll
        for (int r = 0; r < 4; ++r) {
            int rowi = m0 + t * 16 + quad * 4 + r;
            if (rowi < N_NODES) {
                float dv = SCALE ? dis[rowi] : 1.0f;
                #pragma unroll
                for (int c = 0; c < 8; ++c) {
                    int feat = c * 16 + lrow;
                    float z = SCALE ? acc[t][c][r] * dv : acc[t][c][r];
                    Hb[(size_t)rowi * DIM + feat] = f2bf_rne(z);
                }
            }
        }
    }
}

// ---- k_prep: scatter FIRST (R18: latency-bound blocks at t=0), then W
// transposes, then h3s zeroing. R13: CHUNK 2048->1024 (391->782 scatter
// blocks, 1.5->3 per CU) — pure TLP on the latency-bound phase.
__global__ __launch_bounds__(256) void k_prep(const float* __restrict__ W1,
                                              const float* __restrict__ W2,
                                              ushort* __restrict__ W1t,
                                              ushort* __restrict__ W2t,
                                              const int* __restrict__ src,
                                              const int* __restrict__ dst,
                                              uint32_t* __restrict__ gcur,
                                              uint32_t* __restrict__ packed,
                                              float* __restrict__ h3s) {
    __shared__ uint32_t h[NB];
    int b = blockIdx.x;
    int t = threadIdx.x;
    if (b < NBLK) {
        uint32_t dc[CHUNK / 256], sc[CHUNK / 256];   // static-indexed reg cache
        if (t < NB) h[t] = 0u;
        __syncthreads();
        int base = b * CHUNK;
        #pragma unroll
        for (int i = 0; i < CHUNK / 256; ++i) {
            int e = base + i * 256 + t;
            if (e < N_EDGES) {
                dc[i] = (uint32_t)dst[e];
                sc[i] = (uint32_t)src[e];
                atomicAdd(&h[dc[i] >> 8], 1u);
            } else {
                dc[i] = 0xffffffffu;
            }
        }
        __syncthreads();
        if (t < NB) {
            uint32_t c = h[t];
            h[t] = c ? atomicAdd(&gcur[t], c) : 0u;   // reserve contiguous run
        }
        __syncthreads();
        #pragma unroll
        for (int i = 0; i < CHUNK / 256; ++i) {
            if (dc[i] != 0xffffffffu) {
                uint32_t d = dc[i];
                uint32_t s = sc[i];
                uint32_t bk = d >> 8;
                uint32_t pos = atomicAdd(&h[bk], 1u);
                if (pos < CAP)
                    packed[(size_t)bk * CAP + pos] = ((d & 255u) << 16) | s;
            }
        }
    } else if (b < NBLK + 128) {
        int j = (b - NBLK) * 256 + t;              // 0..32767
        const float* W = (j < DIM * DIM) ? W1 : W2;
        ushort* Wt = (j < DIM * DIM) ? W1t : W2t;
        int i = j & (DIM * DIM - 1);
        int k = i >> 7, n = i & 127;
        Wt[n * DIM + k] = f2bf_rne(W[k * DIM + n]);
    } else {
        int idx = (b - NBLK - 128) * 256 + t;      // zero h3s (25000 f32x4)
        if (idx < (N_NODES * 2) / 4) {
            f32x4 z = {0.f, 0.f, 0.f, 0.f};
            ((f32x4*)h3s)[idx] = z;
        }
    }
}

// ---- k_fill: csr blocks (0..195, latency-bound, start at t=0) build the
// compact CSR + dis; gemm blocks (196..586) run layer-1 GEMM concurrently
// (reads only x/W1t — no dependence on csr output; writes UNSCALED Hb).
__global__ __launch_bounds__(256) void k_fill(const uint32_t* __restrict__ gcur,
                                              const uint32_t* __restrict__ packed,
                                              uint32_t* __restrict__ row,
                                              float* __restrict__ dis,
                                              ushort* __restrict__ col16,
                                              const float* __restrict__ x,
                                              const ushort* __restrict__ W1t,
                                              ushort* __restrict__ Hb) {
    __shared__ uint32_t sdeg[256];
    __shared__ uint32_t scan[256];
    __shared__ uint32_t cur[256];
    int b = blockIdx.x;
    int t = threadIdx.x;
    if (b >= NB) {                                  // layer-1 GEMM flavor
        gemm_body<1, 0>(nullptr, x, W1t, nullptr, Hb, b - NB, t);
        return;
    }
    uint32_t n = gcur[b];
    scan[t] = (t < b) ? gcur[t] : 0u;              // b <= 195 < 256
    __syncthreads();
    for (int off = 1; off < 256; off <<= 1) {
        uint32_t xx = (t >= off) ? scan[t - off] : 0u;
        __syncthreads();
        scan[t] += xx;
        __syncthreads();
    }
    uint32_t cbase = scan[255];
    __syncthreads();
    uint32_t pbase = (uint32_t)b * CAP;
    sdeg[t] = 0u;
    __syncthreads();
    for (uint32_t i = t; i < n; i += 256) {
        uint32_t u = packed[pbase + i];
        atomicAdd(&sdeg[u >> 16], 1u);
    }
    __syncthreads();
    uint32_t myd = sdeg[t];
    scan[t] = myd;
    __syncthreads();
    for (int off = 1; off < 256; off <<= 1) {
        uint32_t xx = (t >= off) ? scan[t - off] : 0u;
        __syncthreads();
        scan[t] += xx;
        __syncthreads();
    }
    uint32_t excl = scan[t] - myd;
    cur[t] = excl;
    int v = b * 256 + t;
    if (v <= N_NODES) row[v] = cbase + excl;       // compact; row[50000]=800000
    if (v < N_NODES)  dis[v] = 1.0f / sqrtf((float)(myd + 1u));
    __syncthreads();
    for (uint32_t i = t; i < n; i += 256) {        // re-read: L1-hot, no scratch
        uint32_t u = packed[pbase + i];
        uint32_t pos = cbase + atomicAdd(&cur[u >> 16], 1u);
        col16[pos] = (ushort)(u & 0xffffu);
    }
}

// ---------------- FUSED gather1 + gemm2, 16-node tile, LDS-staged A ----------
// Phase 1: gather (16 lanes/node, 8/4/1 MLP cascade) + bias/leaky/dropout ->
// post-act tile in LDS (XOR-swizzled, G4). Phase 2: 16-row MFMA GEMM from
// LDS; Hb2 dis-prescaled. (R8-best version.)
__global__ __launch_bounds__(256) void k_fused(const uint32_t* __restrict__ row,
                                               const ushort* __restrict__ col16,
                                               const float* __restrict__ dis,
                                               const ushort* __restrict__ Hb,
                                               const float* __restrict__ bias,
                                               const ushort* __restrict__ W2t,
                                               ushort* __restrict__ Hb2,
                                               uint32_t kk0, uint32_t kk1) {
    __shared__ ushort scol[GCAP];
    __shared__ uint32_t srow[GNODES + 1];
    __shared__ ushort At[GNODES * DIM];          // post-act tile, swizzled
    int tid = threadIdx.x;
    int nbase = blockIdx.x * GNODES;
    if (tid <= GNODES) srow[tid] = row[nbase + tid];
    __syncthreads();
    uint32_t eLo = srow[0];
    uint32_t count = srow[GNODES] - eLo;
    bool staged = count <= GCAP;
    if (staged) {
        for (uint32_t i = tid; i < count; i += 256) scol[i] = col16[eLo + i];
    }
    __syncthreads();

    // ---- phase 1: gather + epilogue -> LDS tile ----
    int nl = tid >> 4;                 // node in block (0..15)
    int q  = tid & 15;                 // 8-feat slice (0..15)
    int v = nbase + nl;                // always < N_NODES (50000 = 16*3125)
    float dv = dis[v];
    float acc[8];
    {
        uint4 u = *(const uint4*)(Hb + (size_t)v * DIM + q * 8);
        acc[0] = bfpair_lo(u.x); acc[1] = bfpair_hi(u.x);
        acc[2] = bfpair_lo(u.y); acc[3] = bfpair_hi(u.y);
        acc[4] = bfpair_lo(u.z); acc[5] = bfpair_hi(u.z);
        acc[6] = bfpair_lo(u.w); acc[7] = bfpair_hi(u.w);
        #pragma unroll
        for (int j = 0; j < 8; ++j) acc[j] *= dv;   // self-loop (Hb unscaled)
    }
    uint32_t e0 = srow[nl] - eLo, e1 = srow[nl + 1] - eLo;
    uint32_t e = e0;
    if (staged) {
        for (; e + 8 <= e1; e += 8) {      // 8 rows in flight (MLP)
            uint32_t s0 = scol[e],     s1 = scol[e + 1];
            uint32_t s2 = scol[e + 2], s3 = scol[e + 3];
            uint32_t s4 = scol[e + 4], s5 = scol[e + 5];
            uint32_t s6 = scol[e + 6], s7 = scol[e + 7];
            uint4 u0 = *(const uint4*)(Hb + (size_t)s0 * DIM + q * 8);
            uint4 u1 = *(const uint4*)(Hb + (size_t)s1 * DIM + q * 8);
            uint4 u2 = *(const uint4*)(Hb + (size_t)s2 * DIM + q * 8);
            uint4 u3 = *(const uint4*)(Hb + (size_t)s3 * DIM + q * 8);
            uint4 u4 = *(const uint4*)(Hb + (size_t)s4 * DIM + q * 8);
            uint4 u5 = *(const uint4*)(Hb + (size_t)s5 * DIM + q * 8);
            uint4 u6 = *(const uint4*)(Hb + (size_t)s6 * DIM + q * 8);
            uint4 u7 = *(const uint4*)(Hb + (size_t)s7 * DIM + q * 8);
            float d0 = dis[s0], d1 = dis[s1], d2 = dis[s2], d3 = dis[s3];
            float d4 = dis[s4], d5 = dis[s5], d6 = dis[s6], d7 = dis[s7];
            acc8(acc, u0, d0); acc8(acc, u1, d1);
            acc8(acc, u2, d2); acc8(acc, u3, d3);
            acc8(acc, u4, d4); acc8(acc, u5, d5);
            acc8(acc, u6, d6); acc8(acc, u7, d7);
        }
        for (; e + 4 <= e1; e += 4) {
            uint32_t s0 = scol[e],     s1 = scol[e + 1];
            uint32_t s2 = scol[e + 2], s3 = scol[e + 3];
            uint4 u0 = *(const uint4*)(Hb + (size_t)s0 * DIM + q * 8);
            uint4 u1 = *(const uint4*)(Hb + (size_t)s1 * DIM + q * 8);
            uint4 u2 = *(const uint4*)(Hb + (size_t)s2 * DIM + q * 8);
            uint4 u3 = *(const uint4*)(Hb + (size_t)s3 * DIM + q * 8);
            float d0 = dis[s0], d1 = dis[s1], d2 = dis[s2], d3 = dis[s3];
            acc8(acc, u0, d0); acc8(acc, u1, d1);
            acc8(acc, u2, d2); acc8(acc, u3, d3);
        }
        for (; e < e1; ++e) {
            uint32_t s0 = scol[e];
            uint4 u0 = *(const uint4*)(Hb + (size_t)s0 * DIM + q * 8);
            acc8(acc, u0, dis[s0]);
        }
    } else {
        for (; e < e1; ++e) {
            uint32_t s0 = col16[eLo + e];
            uint4 u0 = *(const uint4*)(Hb + (size_t)s0 * DIM + q * 8);
            acc8(acc, u0, dis[s0]);
        }
    }
    {
        int cbase = q * 8;
        uint32_t ibase = (uint32_t)(v * DIM + cbase);
        ushort8_t o;
        #pragma unroll
        for (int j = 0; j < 8; ++j) {
            float z = acc[j] * dv + bias[cbase + j];
            z = (z >= 0.f) ? z : 0.01f * z;
            z *= drop_scale(kk0, kk1, ibase + j);
            o[j] = f2bf_rne(z);
        }
        // swizzled store: idx = row*128 + (q*8 ^ ((row&7)<<3))
        *((ushort8_t*)(At + nl * DIM + ((q * 8) ^ ((nl & 7) << 3)))) = o;
    }
    __syncthreads();

    // ---- phase 2: 16-row GEMM: Hb2[tile] = (At @ W2) * dis ----
    int w = tid >> 6, lane = tid & 63;
    int lrow = lane & 15, quad = lane >> 4;
    int swz = (lrow & 7) << 3;
    f32x4 acc2[2] = {};
    for (int kt = 0; kt < DIM; kt += 32) {
        int k = kt + quad * 8;
        bfrag a = *(const bfrag*)(At + lrow * DIM + (k ^ swz));
        #pragma unroll
        for (int ct = 0; ct < 2; ++ct) {
            int n = (w * 2 + ct) * 16 + lrow;
            bfrag b = *(const bfrag*)(W2t + (size_t)n * DIM + k);
            acc2[ct] = __builtin_amdgcn_mfma_f32_16x16x32_bf16(a, b, acc2[ct], 0, 0, 0);
        }
    }
    #pragma unroll
    for (int ct = 0; ct < 2; ++ct) {
        #pragma unroll
        for (int rr = 0; rr < 4; ++rr) {
            int rowi = nbase + quad * 4 + rr;
            float dvv = dis[rowi];
            int feat = (w * 2 + ct) * 16 + lrow;
            Hb2[(size_t)rowi * DIM + feat] = f2bf_rne(acc2[ct][rr] * dvv);
        }
    }
}

// ---------------- gather2: aggregation + bias + leaky + dropout + classifier -
// Block = 16 nodes, 16 lanes/node, 8/4/1 cascade. Hb2 rows are dis-prescaled.
// Classifier: 128->2 dot folded in, 16-lane shfl reduce, one atomic pair per
// node into h3s. (R8-best version.)
__global__ __launch_bounds__(256) void k_gather2(const uint32_t* __restrict__ row,
                                                 const ushort* __restrict__ col16,
                                                 const float* __restrict__ dis,
                                                 const ushort* __restrict__ Hb,
                                                 const float* __restrict__ bias,
                                                 const float* __restrict__ W3,
                                                 float* __restrict__ h3s,
                                                 uint32_t kk0, uint32_t kk1) {
    __shared__ ushort scol[GCAP];
    __shared__ uint32_t srow[GNODES + 1];
    int tid = threadIdx.x;
    int nbase = blockIdx.x * GNODES;
    if (tid <= GNODES) srow[tid] = row[nbase + tid];
    __syncthreads();
    uint32_t eLo = srow[0];
    uint32_t count = srow[GNODES] - eLo;
    bool staged = count <= GCAP;
    if (staged) {
        for (uint32_t i = tid; i < count; i += 256) scol[i] = col16[eLo + i];
    }
    __syncthreads();

    int nl = tid >> 4;                 // node in block (0..15)
    int q  = tid & 15;                 // 8-feat slice (0..15)
    int v = nbase + nl;                // always < N_NODES (50000 = 16*3125)
    float dv = dis[v];
    float acc[8];
    {
        uint4 u = *(const uint4*)(Hb + (size_t)v * DIM + q * 8);
        acc[0] = bfpair_lo(u.x); acc[1] = bfpair_hi(u.x);
        acc[2] = bfpair_lo(u.y); acc[3] = bfpair_hi(u.y);
        acc[4] = bfpair_lo(u.z); acc[5] = bfpair_hi(u.z);
        acc[6] = bfpair_lo(u.w); acc[7] = bfpair_hi(u.w);
    }

    uint32_t e0 = srow[nl] - eLo, e1 = srow[nl + 1] - eLo;
    uint32_t e = e0;
    if (staged) {
        for (; e + 8 <= e1; e += 8) {
            uint32_t s0 = scol[e],     s1 = scol[e + 1];
            uint32_t s2 = scol[e + 2], s3 = scol[e + 3];
            uint32_t s4 = scol[e + 4], s5 = scol[e + 5];
            uint32_t s6 = scol[e + 6], s7 = scol[e + 7];
            uint4 u0 = *(const uint4*)(Hb + (size_t)s0 * DIM + q * 8);
            uint4 u1 = *(const uint4*)(Hb + (size_t)s1 * DIM + q * 8);
            uint4 u2 = *(const uint4*)(Hb + (size_t)s2 * DIM + q * 8);
            uint4 u3 = *(const uint4*)(Hb + (size_t)s3 * DIM + q * 8);
            uint4 u4 = *(const uint4*)(Hb + (size_t)s4 * DIM + q * 8);
            uint4 u5 = *(const uint4*)(Hb + (size_t)s5 * DIM + q * 8);
            uint4 u6 = *(const uint4*)(Hb + (size_t)s6 * DIM + q * 8);
            uint4 u7 = *(const uint4*)(Hb + (size_t)s7 * DIM + q * 8);
            acc8p(acc, u0); acc8p(acc, u1); acc8p(acc, u2); acc8p(acc, u3);
            acc8p(acc, u4); acc8p(acc, u5); acc8p(acc, u6); acc8p(acc, u7);
        }
        for (; e + 4 <= e1; e += 4) {
            uint32_t s0 = scol[e],     s1 = scol[e + 1];
            uint32_t s2 = scol[e + 2], s3 = scol[e + 3];
            uint4 u0 = *(const uint4*)(Hb + (size_t)s0 * DIM + q * 8);
            uint4 u1 = *(const uint4*)(Hb + (size_t)s1 * DIM + q * 8);
            uint4 u2 = *(const uint4*)(Hb + (size_t)s2 * DIM + q * 8);
            uint4 u3 = *(const uint4*)(Hb + (size_t)s3 * DIM + q * 8);
            acc8p(acc, u0); acc8p(acc, u1); acc8p(acc, u2); acc8p(acc, u3);
        }
        for (; e < e1; ++e) {
            uint4 u0 = *(const uint4*)(Hb + (size_t)scol[e] * DIM + q * 8);
            acc8p(acc, u0);
        }
    } else {
        for (; e < e1; ++e) {
            uint4 u0 = *(const uint4*)(Hb + (size_t)col16[eLo + e] * DIM + q * 8);
            acc8p(acc, u0);
        }
    }

    int cbase = q * 8;
    uint32_t ibase = (uint32_t)(v * DIM + cbase);
    float o0 = 0.f, o1 = 0.f;
    #pragma unroll
    for (int j = 0; j < 8; ++j) {
        float z = acc[j] * dv + bias[cbase + j];
        z = (z >= 0.f) ? z : 0.01f * z;
        z *= drop_scale(kk0, kk1, ibase + j);
        o0 += z * W3[(cbase + j) * 2 + 0];
        o1 += z * W3[(cbase + j) * 2 + 1];
    }
    // reduce the 16 q-lanes (consecutive lanes, same node)
    o0 += __shfl_xor(o0, 1); o0 += __shfl_xor(o0, 2);
    o0 += __shfl_xor(o0, 4); o0 += __shfl_xor(o0, 8);
    o1 += __shfl_xor(o1, 1); o1 += __shfl_xor(o1, 2);
    o1 += __shfl_xor(o1, 4); o1 += __shfl_xor(o1, 8);
    if (q == 0) {
        atomicAdd(&h3s[v * 2 + 0], o0 * dv);   // src-side dis for layer 3
        atomicAdd(&h3s[v * 2 + 1], o1 * dv);
    }
}

// ---------------- fused layer-3 gather + bias + log_softmax, LDS-staged ------
// 2 lanes/node (alternate edges) halves the divergent serial loop; shfl_xor(1)
// combines the two partials.
__global__ __launch_bounds__(256) void k_gather3(const uint32_t* __restrict__ row,
                                                 const ushort* __restrict__ col16,
                                                 const float* __restrict__ dis,
                                                 const float* __restrict__ H3s,
                                                 const float* __restrict__ b3,
                                                 float* __restrict__ out) {
    __shared__ ushort scol[G3CAP];
    __shared__ uint32_t srow[G3NODES + 1];
    int tid = threadIdx.x;
    int nbase = blockIdx.x * G3NODES;
    int nend = nbase + G3NODES; if (nend > N_NODES) nend = N_NODES;
    int nloc = nend - nbase;
    for (int i = tid; i <= nloc; i += 256) srow[i] = row[nbase + i];
    __syncthreads();
    uint32_t eLo = srow[0];
    uint32_t count = srow[nloc] - eLo;
    bool staged = count <= G3CAP;
    if (staged) {
        for (uint32_t i = tid; i < count; i += 256) scol[i] = col16[eLo + i];
    }
    __syncthreads();

    int nl = tid >> 1;                 // node in block
    int par = tid & 1;                 // edge-parity lane
    int v = nbase + nl;
    if (v >= N_NODES) return;
    const float2* H2 = (const float2*)H3s;
    float z0 = 0.f, z1 = 0.f;
    if (par == 0) {                    // self term once
        float2 h = H2[v];
        z0 = h.x; z1 = h.y;
    }
    uint32_t e0 = srow[nl] - eLo, e1 = srow[nl + 1] - eLo;
    if (staged) {
        for (uint32_t e = e0 + par; e < e1; e += 2) {
            float2 ha = H2[scol[e]];
            z0 += ha.x; z1 += ha.y;
        }
    } else {
        for (uint32_t e = e0 + par; e < e1; e += 2) {
            float2 ha = H2[col16[eLo + e]];
            z0 += ha.x; z1 += ha.y;
        }
    }
    z0 += __shfl_xor(z0, 1);
    z1 += __shfl_xor(z1, 1);
    if (par) return;
    float dv = dis[v];
    z0 = z0 * dv + b3[0];
    z1 = z1 * dv + b3[1];
    float m = fmaxf(z0, z1);
    float lse = m + logf(expf(z0 - m) + expf(z1 - m));
    out[v * 2 + 0] = z0 - lse;
    out[v * 2 + 1] = z1 - lse;
}

extern "C" void kernel_launch(void* const* d_in, const int* in_sizes, int n_in,
                              void* d_out, int out_size, void* d_ws, size_t ws_size,
                              hipStream_t stream) {
    const float* x  = (const float*)d_in[0];
    const int*   ei = (const int*)d_in[1];
    const float* W1 = (const float*)d_in[2];
    const float* b1 = (const float*)d_in[3];
    const float* W2 = (const float*)d_in[4];
    const float* b2 = (const float*)d_in[5];
    const float* W3 = (const float*)d_in[6];
    const float* b3 = (const float*)d_in[7];
    float* out = (float*)d_out;

    const int* src = ei;
    const int* dst = ei + N_EDGES;

    // workspace layout (u32 units) -- R8-verified extents, all disjoint:
    //   gcur   [0, 256)
    //   row    [256, 50304)
    //   dis    [50304, 100352)
    //   packed [100352, 1705984)    (196*8192)
    //   col16  [1705984, 2106112)   (800000 u16 = 400000 u32, padded)
    //   Hb     [2106112, 5306112)   (6.4M u16 = 3.2M u32)
    //   Hb2    [8506112, 11706112)  (6.4M u16 = 3.2M u32)
    //   W1t    [11706112, 11714304)
    //   W2t    [11714304, 11722496)
    //   h3s    [11722496, 11822496)
    uint32_t* wsu = (uint32_t*)d_ws;
    float*    wsf = (float*)d_ws;
    uint32_t* gcur   = wsu;
    uint32_t* row    = wsu + 256;
    float*    dis    = wsf + 50304;
    uint32_t* packed = wsu + 100352;
    ushort*   col16  = (ushort*)(wsu + 1705984);
    ushort*   Hb     = (ushort*)(wsu + 2106112);
    ushort*   Hb2    = (ushort*)(wsu + 8506112);
    ushort*   W1t    = (ushort*)(wsu + 11706112);
    ushort*   W2t    = (ushort*)(wsu + 11714304);
    float*    h3s    = wsf + 11722496;

    // dropout keys: threefry-partitionable fold-like split of key(42) (verified R0)
    uint32_t k1a, k1b, k2a, k2b;
    threefry2x32(0u, 42u, 0u, 0u, k1a, k1b);
    threefry2x32(0u, 42u, 0u, 1u, k2a, k2b);

    hipMemsetAsync(gcur, 0, 256 * sizeof(uint32_t), stream);

    // ---- A: scatter (first!) | W transpose | h3s zero ----
    k_prep<<<NBLK + 128 + ZBLK, 256, 0, stream>>>(W1, W2, W1t, W2t,
                                                  src, dst, gcur, packed, h3s);

    // ---- CSR fill (csr blocks) OVERLAPPED with layer-1 GEMM (gemm blocks) ----
    k_fill<<<NB + 391, 256, 0, stream>>>(gcur, packed, row, dis, col16,
                                         x, W1t, Hb);

    // ---- FUSED: layer-1 gather (+bias/leaky/dropout) + layer-2 GEMM ----
    k_fused<<<GGRID, 256, 0, stream>>>(row, col16, dis, Hb, b1, W2t, Hb2,
                                       k1a, k1b);

    // ---- layer-2 gather + fused classifier ----
    k_gather2<<<GGRID, 256, 0, stream>>>(row, col16, dis, Hb2, b2, W3, h3s,
                                         k2a, k2b);

    // ---- layer 3 aggregate + log_softmax ----
    k_gather3<<<(N_NODES + G3NODES - 1) / G3NODES, 256, 0, stream>>>(row, col16, dis,
                                                                     h3s, b3, out);
}

// Round 14
// 203.266 us; speedup vs baseline: 1.4051x; 1.0402x over previous
//
#include <hip/hip_runtime.h>
#include <stdint.h>

#define N_NODES 50000
#define N_EDGES 800000
#define DIM     128
#define NB   196                 // dst buckets: dst>>8
#define CAP  8192                // fixed slots per bucket in 'packed'
#define CHUNK 2048               // edges per scatter block (R8 value; R13's 1024 hurt)
#define NBLK 391                 // ceil(800000/2048)
#define PT   512                 // k_prep threads (R14: 8 waves/block for TLP)
#define WTBLK 64                 // W transpose blocks: 32768/512
#define ZBLK 49                  // h3s zero blocks: 25000 f32x4 / 512
#define GNODES 16                // nodes per gather/fused block (50000 = 16*3125)
#define GGRID 3125
#define GCAP 2048                // LDS edge cap per block (mean 256)
#define G3NODES 128              // nodes per gather3 block (2 lanes/node)
#define G3CAP 4096               // LDS edge cap for gather3 blocks (mean 2048)

typedef __attribute__((ext_vector_type(8))) unsigned short ushort8_t;
typedef __attribute__((ext_vector_type(8))) short bfrag;    // 8 bf16 = 4 VGPR
typedef __attribute__((ext_vector_type(4))) float f32x4;

// ---------------- Threefry-2x32 (exact JAX 20-round) ----------------
__host__ __device__ inline void threefry2x32(uint32_t k0, uint32_t k1,
                                             uint32_t x0, uint32_t x1,
                                             uint32_t& o0, uint32_t& o1) {
    uint32_t ks0 = k0, ks1 = k1, ks2 = k0 ^ k1 ^ 0x1BD11BDAu;
    uint32_t v0 = x0 + ks0, v1 = x1 + ks1;
#define TF_R(r) { v0 += v1; v1 = (v1 << (r)) | (v1 >> (32 - (r))); v1 ^= v0; }
    TF_R(13) TF_R(15) TF_R(26) TF_R(6)
    v0 += ks1; v1 += ks2 + 1u;
    TF_R(17) TF_R(29) TF_R(16) TF_R(24)
    v0 += ks2; v1 += ks0 + 2u;
    TF_R(13) TF_R(15) TF_R(26) TF_R(6)
    v0 += ks0; v1 += ks1 + 3u;
    TF_R(17) TF_R(29) TF_R(16) TF_R(24)
    v0 += ks1; v1 += ks2 + 4u;
    TF_R(13) TF_R(15) TF_R(26) TF_R(6)
    v0 += ks2; v1 += ks0 + 5u;
#undef TF_R
    o0 = v0; o1 = v1;
}

__device__ inline float drop_scale(uint32_t kk0, uint32_t kk1, uint32_t i) {
    uint32_t b0, b1;
    threefry2x32(kk0, kk1, 0u, i, b0, b1);
    uint32_t bits = b0 ^ b1;               // partitionable 32-bit path (verified R0)
    return (bits >> 31) ? 0.0f : 2.0f;     // keep iff u < 0.5 iff top bit 0
}

__device__ inline float bf2f(ushort u) {
    return __uint_as_float(((uint32_t)u) << 16);
}
__device__ inline float bfpair_lo(uint32_t u) { return __uint_as_float(u << 16); }
__device__ inline float bfpair_hi(uint32_t u) { return __uint_as_float(u & 0xffff0000u); }

__device__ inline ushort f2bf_rne(float f) {
    uint32_t bits = __float_as_uint(f);
    uint32_t lsb = (bits >> 16) & 1u;
    bits += 0x7fffu + lsb;                 // round-to-nearest-even
    return (ushort)(bits >> 16);
}

// 8-feat accumulate from a uint4 of bf16 pairs (dword-wise unpack: 1 VALU/elem)
__device__ inline void acc8(float* acc, uint4 u, float d) {
    acc[0] += d * bfpair_lo(u.x); acc[1] += d * bfpair_hi(u.x);
    acc[2] += d * bfpair_lo(u.y); acc[3] += d * bfpair_hi(u.y);
    acc[4] += d * bfpair_lo(u.z); acc[5] += d * bfpair_hi(u.z);
    acc[6] += d * bfpair_lo(u.w); acc[7] += d * bfpair_hi(u.w);
}
__device__ inline void acc8p(float* acc, uint4 u) {
    acc[0] += bfpair_lo(u.x); acc[1] += bfpair_hi(u.x);
    acc[2] += bfpair_lo(u.y); acc[3] += bfpair_hi(u.y);
    acc[4] += bfpair_lo(u.z); acc[5] += bfpair_hi(u.z);
    acc[6] += bfpair_lo(u.w); acc[7] += bfpair_hi(u.w);
}

// ---------------- MFMA GEMM body (layer-1 inside k_fill): Hb[v][128] --------
// F32A=1: A read from fp32, converted in registers. SCALE=0: raw output
// (dis not ready while csr blocks run; gather applies dis[s] per edge).
template<int F32A, int SCALE>
__device__ inline void gemm_body(const ushort* __restrict__ Xb,
                                 const float* __restrict__ Xf,
                                 const ushort* __restrict__ Wt,
                                 const float* __restrict__ dis,
                                 ushort* __restrict__ Hb, int gb, int tid) {
    int w = tid >> 6, lane = tid & 63;
    int m0 = gb * 128 + w * 32;
    int lrow = lane & 15, quad = lane >> 4;
    f32x4 acc[2][8] = {};
    for (int kt = 0; kt < DIM; kt += 32) {
        bfrag a[2], b[8];
        #pragma unroll
        for (int t = 0; t < 2; ++t) {
            int m = m0 + t * 16 + lrow;
            if (m >= N_NODES) m = 0;
            if (F32A) {
                const float* p = Xf + (size_t)m * DIM + kt + quad * 8;
                f32x4 v0 = *(const f32x4*)p;
                f32x4 v1 = *(const f32x4*)(p + 4);
                #pragma unroll
                for (int j = 0; j < 4; ++j) {
                    a[t][j]     = (short)f2bf_rne(v0[j]);
                    a[t][j + 4] = (short)f2bf_rne(v1[j]);
                }
            } else {
                a[t] = *(const bfrag*)(Xb + (size_t)m * DIM + kt + quad * 8);
            }
        }
        #pragma unroll
        for (int c = 0; c < 8; ++c) {
            int n = c * 16 + lrow;
            b[c] = *(const bfrag*)(Wt + (size_t)n * DIM + kt + quad * 8);
        }
        #pragma unroll
        for (int t = 0; t < 2; ++t)
            #pragma unroll
            for (int c = 0; c < 8; ++c)
                acc[t][c] = __builtin_amdgcn_mfma_f32_16x16x32_bf16(a[t], b[c], acc[t][c], 0, 0, 0);
    }
    #pragma unroll
    for (int t = 0; t < 2; ++t) {
        #pragma unroll
        for (int r = 0; r < 4; ++r) {
            int rowi = m0 + t * 16 + quad * 4 + r;
            if (rowi < N_NODES) {
                float dv = SCALE ? dis[rowi] : 1.0f;
                #pragma unroll
                for (int c = 0; c < 8; ++c) {
                    int feat = c * 16 + lrow;
                    float z = SCALE ? acc[t][c][r] * dv : acc[t][c][r];
                    Hb[(size_t)rowi * DIM + feat] = f2bf_rne(z);
                }
            }
        }
    }
}

// ---- k_prep: scatter FIRST (R18: latency-bound blocks at t=0), then W
// transposes, then h3s zeroing. R14: 512-thread blocks — same CHUNK=2048 and
// per-block overhead as R8, but 8 waves/block (2x latency hiding; R13's
// chunk-halving doubled overhead instead and regressed).
__global__ __launch_bounds__(512) void k_prep(const float* __restrict__ W1,
                                              const float* __restrict__ W2,
                                              ushort* __restrict__ W1t,
                                              ushort* __restrict__ W2t,
                                              const int* __restrict__ src,
                                              const int* __restrict__ dst,
                                              uint32_t* __restrict__ gcur,
                                              uint32_t* __restrict__ packed,
                                              float* __restrict__ h3s) {
    __shared__ uint32_t h[NB];
    int b = blockIdx.x;
    int t = threadIdx.x;
    if (b < NBLK) {
        uint32_t dc[CHUNK / PT], sc[CHUNK / PT];     // static-indexed reg cache
        if (t < NB) h[t] = 0u;
        __syncthreads();
        int base = b * CHUNK;
        #pragma unroll
        for (int i = 0; i < CHUNK / PT; ++i) {
            int e = base + i * PT + t;
            if (e < N_EDGES) {
                dc[i] = (uint32_t)dst[e];
                sc[i] = (uint32_t)src[e];
                atomicAdd(&h[dc[i] >> 8], 1u);
            } else {
                dc[i] = 0xffffffffu;
            }
        }
        __syncthreads();
        if (t < NB) {
            uint32_t c = h[t];
            h[t] = c ? atomicAdd(&gcur[t], c) : 0u;   // reserve contiguous run
        }
        __syncthreads();
        #pragma unroll
        for (int i = 0; i < CHUNK / PT; ++i) {
            if (dc[i] != 0xffffffffu) {
                uint32_t d = dc[i];
                uint32_t s = sc[i];
                uint32_t bk = d >> 8;
                uint32_t pos = atomicAdd(&h[bk], 1u);
                if (pos < CAP)
                    packed[(size_t)bk * CAP + pos] = ((d & 255u) << 16) | s;
            }
        }
    } else if (b < NBLK + WTBLK) {
        int j = (b - NBLK) * PT + t;               // 0..32767
        const float* W = (j < DIM * DIM) ? W1 : W2;
        ushort* Wt = (j < DIM * DIM) ? W1t : W2t;
        int i = j & (DIM * DIM - 1);
        int k = i >> 7, n = i & 127;
        Wt[n * DIM + k] = f2bf_rne(W[k * DIM + n]);
    } else {
        int idx = (b - NBLK - WTBLK) * PT + t;     // zero h3s (25000 f32x4)
        if (idx < (N_NODES * 2) / 4) {
            f32x4 z = {0.f, 0.f, 0.f, 0.f};
            ((f32x4*)h3s)[idx] = z;
        }
    }
}

// ---- k_fill: csr blocks (0..195, latency-bound, start at t=0) build the
// compact CSR + dis; gemm blocks (196..586) run layer-1 GEMM concurrently
// (reads only x/W1t — no dependence on csr output; writes UNSCALED Hb).
__global__ __launch_bounds__(256) void k_fill(const uint32_t* __restrict__ gcur,
                                              const uint32_t* __restrict__ packed,
                                              uint32_t* __restrict__ row,
                                              float* __restrict__ dis,
                                              ushort* __restrict__ col16,
                                              const float* __restrict__ x,
                                              const ushort* __restrict__ W1t,
                                              ushort* __restrict__ Hb) {
    __shared__ uint32_t sdeg[256];
    __shared__ uint32_t scan[256];
    __shared__ uint32_t cur[256];
    int b = blockIdx.x;
    int t = threadIdx.x;
    if (b >= NB) {                                  // layer-1 GEMM flavor
        gemm_body<1, 0>(nullptr, x, W1t, nullptr, Hb, b - NB, t);
        return;
    }
    uint32_t n = gcur[b];
    scan[t] = (t < b) ? gcur[t] : 0u;              // b <= 195 < 256
    __syncthreads();
    for (int off = 1; off < 256; off <<= 1) {
        uint32_t xx = (t >= off) ? scan[t - off] : 0u;
        __syncthreads();
        scan[t] += xx;
        __syncthreads();
    }
    uint32_t cbase = scan[255];
    __syncthreads();
    uint32_t pbase = (uint32_t)b * CAP;
    sdeg[t] = 0u;
    __syncthreads();
    for (uint32_t i = t; i < n; i += 256) {
        uint32_t u = packed[pbase + i];
        atomicAdd(&sdeg[u >> 16], 1u);
    }
    __syncthreads();
    uint32_t myd = sdeg[t];
    scan[t] = myd;
    __syncthreads();
    for (int off = 1; off < 256; off <<= 1) {
        uint32_t xx = (t >= off) ? scan[t - off] : 0u;
        __syncthreads();
        scan[t] += xx;
        __syncthreads();
    }
    uint32_t excl = scan[t] - myd;
    cur[t] = excl;
    int v = b * 256 + t;
    if (v <= N_NODES) row[v] = cbase + excl;       // compact; row[50000]=800000
    if (v < N_NODES)  dis[v] = 1.0f / sqrtf((float)(myd + 1u));
    __syncthreads();
    for (uint32_t i = t; i < n; i += 256) {        // re-read: L1-hot, no scratch
        uint32_t u = packed[pbase + i];
        uint32_t pos = cbase + atomicAdd(&cur[u >> 16], 1u);
        col16[pos] = (ushort)(u & 0xffffu);
    }
}

// ---------------- FUSED gather1 + gemm2, 16-node tile, LDS-staged A ----------
// Phase 1: gather (16 lanes/node, 8/4/1 MLP cascade) + bias/leaky/dropout ->
// post-act tile in LDS (XOR-swizzled, G4). Phase 2: 16-row MFMA GEMM from
// LDS; Hb2 dis-prescaled. (R8-best version.)
__global__ __launch_bounds__(256) void k_fused(const uint32_t* __restrict__ row,
                                               const ushort* __restrict__ col16,
                                               const float* __restrict__ dis,
                                               const ushort* __restrict__ Hb,
                                               const float* __restrict__ bias,
                                               const ushort* __restrict__ W2t,
                                               ushort* __restrict__ Hb2,
                                               uint32_t kk0, uint32_t kk1) {
    __shared__ ushort scol[GCAP];
    __shared__ uint32_t srow[GNODES + 1];
    __shared__ ushort At[GNODES * DIM];          // post-act tile, swizzled
    int tid = threadIdx.x;
    int nbase = blockIdx.x * GNODES;
    if (tid <= GNODES) srow[tid] = row[nbase + tid];
    __syncthreads();
    uint32_t eLo = srow[0];
    uint32_t count = srow[GNODES] - eLo;
    bool staged = count <= GCAP;
    if (staged) {
        for (uint32_t i = tid; i < count; i += 256) scol[i] = col16[eLo + i];
    }
    __syncthreads();

    // ---- phase 1: gather + epilogue -> LDS tile ----
    int nl = tid >> 4;                 // node in block (0..15)
    int q  = tid & 15;                 // 8-feat slice (0..15)
    int v = nbase + nl;                // always < N_NODES (50000 = 16*3125)
    float dv = dis[v];
    float acc[8];
    {
        uint4 u = *(const uint4*)(Hb + (size_t)v * DIM + q * 8);
        acc[0] = bfpair_lo(u.x); acc[1] = bfpair_hi(u.x);
        acc[2] = bfpair_lo(u.y); acc[3] = bfpair_hi(u.y);
        acc[4] = bfpair_lo(u.z); acc[5] = bfpair_hi(u.z);
        acc[6] = bfpair_lo(u.w); acc[7] = bfpair_hi(u.w);
        #pragma unroll
        for (int j = 0; j < 8; ++j) acc[j] *= dv;   // self-loop (Hb unscaled)
    }
    uint32_t e0 = srow[nl] - eLo, e1 = srow[nl + 1] - eLo;
    uint32_t e = e0;
    if (staged) {
        for (; e + 8 <= e1; e += 8) {      // 8 rows in flight (MLP)
            uint32_t s0 = scol[e],     s1 = scol[e + 1];
            uint32_t s2 = scol[e + 2], s3 = scol[e + 3];
            uint32_t s4 = scol[e + 4], s5 = scol[e + 5];
            uint32_t s6 = scol[e + 6], s7 = scol[e + 7];
            uint4 u0 = *(const uint4*)(Hb + (size_t)s0 * DIM + q * 8);
            uint4 u1 = *(const uint4*)(Hb + (size_t)s1 * DIM + q * 8);
            uint4 u2 = *(const uint4*)(Hb + (size_t)s2 * DIM + q * 8);
            uint4 u3 = *(const uint4*)(Hb + (size_t)s3 * DIM + q * 8);
            uint4 u4 = *(const uint4*)(Hb + (size_t)s4 * DIM + q * 8);
            uint4 u5 = *(const uint4*)(Hb + (size_t)s5 * DIM + q * 8);
            uint4 u6 = *(const uint4*)(Hb + (size_t)s6 * DIM + q * 8);
            uint4 u7 = *(const uint4*)(Hb + (size_t)s7 * DIM + q * 8);
            float d0 = dis[s0], d1 = dis[s1], d2 = dis[s2], d3 = dis[s3];
            float d4 = dis[s4], d5 = dis[s5], d6 = dis[s6], d7 = dis[s7];
            acc8(acc, u0, d0); acc8(acc, u1, d1);
            acc8(acc, u2, d2); acc8(acc, u3, d3);
            acc8(acc, u4, d4); acc8(acc, u5, d5);
            acc8(acc, u6, d6); acc8(acc, u7, d7);
        }
        for (; e + 4 <= e1; e += 4) {
            uint32_t s0 = scol[e],     s1 = scol[e + 1];
            uint32_t s2 = scol[e + 2], s3 = scol[e + 3];
            uint4 u0 = *(const uint4*)(Hb + (size_t)s0 * DIM + q * 8);
            uint4 u1 = *(const uint4*)(Hb + (size_t)s1 * DIM + q * 8);
            uint4 u2 = *(const uint4*)(Hb + (size_t)s2 * DIM + q * 8);
            uint4 u3 = *(const uint4*)(Hb + (size_t)s3 * DIM + q * 8);
            float d0 = dis[s0], d1 = dis[s1], d2 = dis[s2], d3 = dis[s3];
            acc8(acc, u0, d0); acc8(acc, u1, d1);
            acc8(acc, u2, d2); acc8(acc, u3, d3);
        }
        for (; e < e1; ++e) {
            uint32_t s0 = scol[e];
            uint4 u0 = *(const uint4*)(Hb + (size_t)s0 * DIM + q * 8);
            acc8(acc, u0, dis[s0]);
        }
    } else {
        for (; e < e1; ++e) {
            uint32_t s0 = col16[eLo + e];
            uint4 u0 = *(const uint4*)(Hb + (size_t)s0 * DIM + q * 8);
            acc8(acc, u0, dis[s0]);
        }
    }
    {
        int cbase = q * 8;
        uint32_t ibase = (uint32_t)(v * DIM + cbase);
        ushort8_t o;
        #pragma unroll
        for (int j = 0; j < 8; ++j) {
            float z = acc[j] * dv + bias[cbase + j];
            z = (z >= 0.f) ? z : 0.01f * z;
            z *= drop_scale(kk0, kk1, ibase + j);
            o[j] = f2bf_rne(z);
        }
        // swizzled store: idx = row*128 + (q*8 ^ ((row&7)<<3))
        *((ushort8_t*)(At + nl * DIM + ((q * 8) ^ ((nl & 7) << 3)))) = o;
    }
    __syncthreads();

    // ---- phase 2: 16-row GEMM: Hb2[tile] = (At @ W2) * dis ----
    int w = tid >> 6, lane = tid & 63;
    int lrow = lane & 15, quad = lane >> 4;
    int swz = (lrow & 7) << 3;
    f32x4 acc2[2] = {};
    for (int kt = 0; kt < DIM; kt += 32) {
        int k = kt + quad * 8;
        bfrag a = *(const bfrag*)(At + lrow * DIM + (k ^ swz));
        #pragma unroll
        for (int ct = 0; ct < 2; ++ct) {
            int n = (w * 2 + ct) * 16 + lrow;
            bfrag b = *(const bfrag*)(W2t + (size_t)n * DIM + k);
            acc2[ct] = __builtin_amdgcn_mfma_f32_16x16x32_bf16(a, b, acc2[ct], 0, 0, 0);
        }
    }
    #pragma unroll
    for (int ct = 0; ct < 2; ++ct) {
        #pragma unroll
        for (int rr = 0; rr < 4; ++rr) {
            int rowi = nbase + quad * 4 + rr;
            float dvv = dis[rowi];
            int feat = (w * 2 + ct) * 16 + lrow;
            Hb2[(size_t)rowi * DIM + feat] = f2bf_rne(acc2[ct][rr] * dvv);
        }
    }
}

// ---------------- gather2: aggregation + bias + leaky + dropout + classifier -
// Block = 16 nodes, 16 lanes/node, 8/4/1 cascade. Hb2 rows are dis-prescaled.
// Classifier: 128->2 dot folded in, 16-lane shfl reduce, one atomic pair per
// node into h3s. (R8-best version.)
__global__ __launch_bounds__(256) void k_gather2(const uint32_t* __restrict__ row,
                                                 const ushort* __restrict__ col16,
                                                 const float* __restrict__ dis,
                                                 const ushort* __restrict__ Hb,
                                                 const float* __restrict__ bias,
                                                 const float* __restrict__ W3,
                                                 float* __restrict__ h3s,
                                                 uint32_t kk0, uint32_t kk1) {
    __shared__ ushort scol[GCAP];
    __shared__ uint32_t srow[GNODES + 1];
    int tid = threadIdx.x;
    int nbase = blockIdx.x * GNODES;
    if (tid <= GNODES) srow[tid] = row[nbase + tid];
    __syncthreads();
    uint32_t eLo = srow[0];
    uint32_t count = srow[GNODES] - eLo;
    bool staged = count <= GCAP;
    if (staged) {
        for (uint32_t i = tid; i < count; i += 256) scol[i] = col16[eLo + i];
    }
    __syncthreads();

    int nl = tid >> 4;                 // node in block (0..15)
    int q  = tid & 15;                 // 8-feat slice (0..15)
    int v = nbase + nl;                // always < N_NODES (50000 = 16*3125)
    float dv = dis[v];
    float acc[8];
    {
        uint4 u = *(const uint4*)(Hb + (size_t)v * DIM + q * 8);
        acc[0] = bfpair_lo(u.x); acc[1] = bfpair_hi(u.x);
        acc[2] = bfpair_lo(u.y); acc[3] = bfpair_hi(u.y);
        acc[4] = bfpair_lo(u.z); acc[5] = bfpair_hi(u.z);
        acc[6] = bfpair_lo(u.w); acc[7] = bfpair_hi(u.w);
    }

    uint32_t e0 = srow[nl] - eLo, e1 = srow[nl + 1] - eLo;
    uint32_t e = e0;
    if (staged) {
        for (; e + 8 <= e1; e += 8) {
            uint32_t s0 = scol[e],     s1 = scol[e + 1];
            uint32_t s2 = scol[e + 2], s3 = scol[e + 3];
            uint32_t s4 = scol[e + 4], s5 = scol[e + 5];
            uint32_t s6 = scol[e + 6], s7 = scol[e + 7];
            uint4 u0 = *(const uint4*)(Hb + (size_t)s0 * DIM + q * 8);
            uint4 u1 = *(const uint4*)(Hb + (size_t)s1 * DIM + q * 8);
            uint4 u2 = *(const uint4*)(Hb + (size_t)s2 * DIM + q * 8);
            uint4 u3 = *(const uint4*)(Hb + (size_t)s3 * DIM + q * 8);
            uint4 u4 = *(const uint4*)(Hb + (size_t)s4 * DIM + q * 8);
            uint4 u5 = *(const uint4*)(Hb + (size_t)s5 * DIM + q * 8);
            uint4 u6 = *(const uint4*)(Hb + (size_t)s6 * DIM + q * 8);
            uint4 u7 = *(const uint4*)(Hb + (size_t)s7 * DIM + q * 8);
            acc8p(acc, u0); acc8p(acc, u1); acc8p(acc, u2); acc8p(acc, u3);
            acc8p(acc, u4); acc8p(acc, u5); acc8p(acc, u6); acc8p(acc, u7);
        }
        for (; e + 4 <= e1; e += 4) {
            uint32_t s0 = scol[e],     s1 = scol[e + 1];
            uint32_t s2 = scol[e + 2], s3 = scol[e + 3];
            uint4 u0 = *(const uint4*)(Hb + (size_t)s0 * DIM + q * 8);
            uint4 u1 = *(const uint4*)(Hb + (size_t)s1 * DIM + q * 8);
            uint4 u2 = *(const uint4*)(Hb + (size_t)s2 * DIM + q * 8);
            uint4 u3 = *(const uint4*)(Hb + (size_t)s3 * DIM + q * 8);
            acc8p(acc, u0); acc8p(acc, u1); acc8p(acc, u2); acc8p(acc, u3);
        }
        for (; e < e1; ++e) {
            uint4 u0 = *(const uint4*)(Hb + (size_t)scol[e] * DIM + q * 8);
            acc8p(acc, u0);
        }
    } else {
        for (; e < e1; ++e) {
            uint4 u0 = *(const uint4*)(Hb + (size_t)col16[eLo + e] * DIM + q * 8);
            acc8p(acc, u0);
        }
    }

    int cbase = q * 8;
    uint32_t ibase = (uint32_t)(v * DIM + cbase);
    float o0 = 0.f, o1 = 0.f;
    #pragma unroll
    for (int j = 0; j < 8; ++j) {
        float z = acc[j] * dv + bias[cbase + j];
        z = (z >= 0.f) ? z : 0.01f * z;
        z *= drop_scale(kk0, kk1, ibase + j);
        o0 += z * W3[(cbase + j) * 2 + 0];
        o1 += z * W3[(cbase + j) * 2 + 1];
    }
    // reduce the 16 q-lanes (consecutive lanes, same node)
    o0 += __shfl_xor(o0, 1); o0 += __shfl_xor(o0, 2);
    o0 += __shfl_xor(o0, 4); o0 += __shfl_xor(o0, 8);
    o1 += __shfl_xor(o1, 1); o1 += __shfl_xor(o1, 2);
    o1 += __shfl_xor(o1, 4); o1 += __shfl_xor(o1, 8);
    if (q == 0) {
        atomicAdd(&h3s[v * 2 + 0], o0 * dv);   // src-side dis for layer 3
        atomicAdd(&h3s[v * 2 + 1], o1 * dv);
    }
}

// ---------------- fused layer-3 gather + bias + log_softmax, LDS-staged ------
// 2 lanes/node (alternate edges) halves the divergent serial loop; shfl_xor(1)
// combines the two partials.
__global__ __launch_bounds__(256) void k_gather3(const uint32_t* __restrict__ row,
                                                 const ushort* __restrict__ col16,
                                                 const float* __restrict__ dis,
                                                 const float* __restrict__ H3s,
                                                 const float* __restrict__ b3,
                                                 float* __restrict__ out) {
    __shared__ ushort scol[G3CAP];
    __shared__ uint32_t srow[G3NODES + 1];
    int tid = threadIdx.x;
    int nbase = blockIdx.x * G3NODES;
    int nend = nbase + G3NODES; if (nend > N_NODES) nend = N_NODES;
    int nloc = nend - nbase;
    for (int i = tid; i <= nloc; i += 256) srow[i] = row[nbase + i];
    __syncthreads();
    uint32_t eLo = srow[0];
    uint32_t count = srow[nloc] - eLo;
    bool staged = count <= G3CAP;
    if (staged) {
        for (uint32_t i = tid; i < count; i += 256) scol[i] = col16[eLo + i];
    }
    __syncthreads();

    int nl = tid >> 1;                 // node in block
    int par = tid & 1;                 // edge-parity lane
    int v = nbase + nl;
    if (v >= N_NODES) return;
    const float2* H2 = (const float2*)H3s;
    float z0 = 0.f, z1 = 0.f;
    if (par == 0) {                    // self term once
        float2 h = H2[v];
        z0 = h.x; z1 = h.y;
    }
    uint32_t e0 = srow[nl] - eLo, e1 = srow[nl + 1] - eLo;
    if (staged) {
        for (uint32_t e = e0 + par; e < e1; e += 2) {
            float2 ha = H2[scol[e]];
            z0 += ha.x; z1 += ha.y;
        }
    } else {
        for (uint32_t e = e0 + par; e < e1; e += 2) {
            float2 ha = H2[col16[eLo + e]];
            z0 += ha.x; z1 += ha.y;
        }
    }
    z0 += __shfl_xor(z0, 1);
    z1 += __shfl_xor(z1, 1);
    if (par) return;
    float dv = dis[v];
    z0 = z0 * dv + b3[0];
    z1 = z1 * dv + b3[1];
    float m = fmaxf(z0, z1);
    float lse = m + logf(expf(z0 - m) + expf(z1 - m));
    out[v * 2 + 0] = z0 - lse;
    out[v * 2 + 1] = z1 - lse;
}

extern "C" void kernel_launch(void* const* d_in, const int* in_sizes, int n_in,
                              void* d_out, int out_size, void* d_ws, size_t ws_size,
                              hipStream_t stream) {
    const float* x  = (const float*)d_in[0];
    const int*   ei = (const int*)d_in[1];
    const float* W1 = (const float*)d_in[2];
    const float* b1 = (const float*)d_in[3];
    const float* W2 = (const float*)d_in[4];
    const float* b2 = (const float*)d_in[5];
    const float* W3 = (const float*)d_in[6];
    const float* b3 = (const float*)d_in[7];
    float* out = (float*)d_out;

    const int* src = ei;
    const int* dst = ei + N_EDGES;

    // workspace layout (u32 units) -- R8-verified extents, all disjoint:
    //   gcur   [0, 256)
    //   row    [256, 50304)
    //   dis    [50304, 100352)
    //   packed [100352, 1705984)    (196*8192)
    //   col16  [1705984, 2106112)   (800000 u16 = 400000 u32, padded)
    //   Hb     [2106112, 5306112)   (6.4M u16 = 3.2M u32)
    //   Hb2    [8506112, 11706112)  (6.4M u16 = 3.2M u32)
    //   W1t    [11706112, 11714304)
    //   W2t    [11714304, 11722496)
    //   h3s    [11722496, 11822496)
    uint32_t* wsu = (uint32_t*)d_ws;
    float*    wsf = (float*)d_ws;
    uint32_t* gcur   = wsu;
    uint32_t* row    = wsu + 256;
    float*    dis    = wsf + 50304;
    uint32_t* packed = wsu + 100352;
    ushort*   col16  = (ushort*)(wsu + 1705984);
    ushort*   Hb     = (ushort*)(wsu + 2106112);
    ushort*   Hb2    = (ushort*)(wsu + 8506112);
    ushort*   W1t    = (ushort*)(wsu + 11706112);
    ushort*   W2t    = (ushort*)(wsu + 11714304);
    float*    h3s    = wsf + 11722496;

    // dropout keys: threefry-partitionable fold-like split of key(42) (verified R0)
    uint32_t k1a, k1b, k2a, k2b;
    threefry2x32(0u, 42u, 0u, 0u, k1a, k1b);
    threefry2x32(0u, 42u, 0u, 1u, k2a, k2b);

    hipMemsetAsync(gcur, 0, 256 * sizeof(uint32_t), stream);

    // ---- A: scatter (first!) | W transpose | h3s zero (512-thread blocks) ----
    k_prep<<<NBLK + WTBLK + ZBLK, PT, 0, stream>>>(W1, W2, W1t, W2t,
                                                   src, dst, gcur, packed, h3s);

    // ---- CSR fill (csr blocks) OVERLAPPED with layer-1 GEMM (gemm blocks) ----
    k_fill<<<NB + 391, 256, 0, stream>>>(gcur, packed, row, dis, col16,
                                         x, W1t, Hb);

    // ---- FUSED: layer-1 gather (+bias/leaky/dropout) + layer-2 GEMM ----
    k_fused<<<GGRID, 256, 0, stream>>>(row, col16, dis, Hb, b1, W2t, Hb2,
                                       k1a, k1b);

    // ---- layer-2 gather + fused classifier ----
    k_gather2<<<GGRID, 256, 0, stream>>>(row, col16, dis, Hb2, b2, W3, h3s,
                                         k2a, k2b);

    // ---- layer 3 aggregate + log_softmax ----
    k_gather3<<<(N_NODES + G3NODES - 1) / G3NODES, 256, 0, stream>>>(row, col16, dis,
                                                                     h3s, b3, out);
}